// Round 5
// baseline (214.388 us; speedup 1.0000x reference)
//
#include <hip/hip_runtime.h>

// Problem dims (fixed by setup_inputs)
#define BATCH 4
#define HH 128
#define WW 128
#define CC 128
#define BIN 64
#define NPIX (BATCH * HH * WW)   // 65536

typedef short bf16x8 __attribute__((ext_vector_type(8)));
typedef float f32x4 __attribute__((ext_vector_type(4)));

// round-to-nearest-even bf16 bits of f
__device__ __forceinline__ unsigned bf_hi(float f) {
    unsigned u = __float_as_uint(f);
    return (u + 0x7fffu + ((u >> 16) & 1u)) >> 16;
}
// A-operand split: per c, k' slots [4c..4c+3] = [xh, xh, xl, xl]
__device__ __forceinline__ uint2 split_aa(float f) {
    unsigned hb = bf_hi(f);
    float lo = f - __uint_as_float(hb << 16);
    unsigned lb = bf_hi(lo);
    return make_uint2(hb | (hb << 16), lb | (lb << 16));
}

// ---------------------------------------------------------------------------
// Kernel 0: pre-split W (both convs) into bf16 [conv][d][k'=4c+slot],
// slots [wh, wl, wh, wl] (matches A's [xh,xh,xl,xl] -> full fp32 product).
// Output lives in d_out (256 KB of 16.8 MB) -- attn fully overwrites d_out
// afterwards, stream-ordered.
// ---------------------------------------------------------------------------
__global__ void presplit_w_kernel(const float* __restrict__ Wm,
                                  const float* __restrict__ Wr,
                                  unsigned short* __restrict__ WS) {
    const int t = blockIdx.x * 256 + threadIdx.x;   // 32768 total
    const int conv = t >> 14;
    const int d = (t >> 7) & 127;
    const int c = t & 127;
    const float* W = conv ? Wr : Wm;
    const float f = W[c * CC + d];
    const unsigned hb = bf_hi(f);
    const float lo = f - __uint_as_float(hb << 16);
    const unsigned lb = bf_hi(lo);
    const unsigned pk = hb | (lb << 16);            // [wh, wl]
    *(uint2*)(WS + ((size_t)conv * 128 + d) * 512 + c * 4) = make_uint2(pk, pk);
}

// ---------------------------------------------------------------------------
// Kernel 1: 1x1 conv via split-bf16 MFMA, restructured:
//  - A-tile (128 px x 16 c per iter) double-buffered in LDS, register
//    prefetch of iter k+1 -> ONE barrier per iter, no global latency behind it
//  - B-frags straight from pre-split global W (L2-hot, no barrier dependency)
// Row pad 72 shorts: staging writes & frag reads are 2-way (free).
// ---------------------------------------------------------------------------
#define AROW 72

__global__ __launch_bounds__(256, 3)
void conv_mfma_kernel(const float* __restrict__ Xm, const float* __restrict__ Xr,
                      const unsigned short* __restrict__ Wsplit,
                      float* __restrict__ Ym, float* __restrict__ Yr) {
    const float* __restrict__ X = blockIdx.y ? Xr : Xm;
    const unsigned short* __restrict__ WS = Wsplit + (size_t)blockIdx.y * 128 * 512;
    float* __restrict__ Y = blockIdx.y ? Yr : Ym;

    __shared__ unsigned short AT[2][128 * AROW];   // 2 x 18 KB

    const int t  = threadIdx.x;
    const int wv = t >> 6;
    const int l  = t & 63;
    const int wm = (wv >> 1) * 64;
    const int wn = (wv & 1) * 64;
    const int lr = l & 15;
    const int lq = l >> 4;
    const int p_base = blockIdx.x * 128;
    const int px = t >> 1, ahalf = t & 1;   // 2 threads/px, 8 c each per iter

    f32x4 acc[4][4] = {};

    const float* xbase = X + (size_t)(p_base + px) * CC + ahalf * 8;
    float4 pa0 = *(const float4*)(xbase);
    float4 pa1 = *(const float4*)(xbase + 4);

    for (int k = 0; k < 8; ++k) {           // 16 c per iter
        // split prefetched regs -> AT[k&1]
        {
            unsigned short* arow = &AT[k & 1][px * AROW + ahalf * 32];
            uint2 a0 = split_aa(pa0.x), a1 = split_aa(pa0.y),
                  a2 = split_aa(pa0.z), a3 = split_aa(pa0.w);
            *(uint4*)(arow)     = make_uint4(a0.x, a0.y, a1.x, a1.y);
            *(uint4*)(arow + 8) = make_uint4(a2.x, a2.y, a3.x, a3.y);
            uint2 b0 = split_aa(pa1.x), b1 = split_aa(pa1.y),
                  b2 = split_aa(pa1.z), b3 = split_aa(pa1.w);
            *(uint4*)(arow + 16) = make_uint4(b0.x, b0.y, b1.x, b1.y);
            *(uint4*)(arow + 24) = make_uint4(b2.x, b2.y, b3.x, b3.y);
        }
        __syncthreads();
        // prefetch next A chunk (lands during MFMA below)
        if (k < 7) {
            const float* xp = xbase + (k + 1) * 16;
            pa0 = *(const float4*)(xp);
            pa1 = *(const float4*)(xp + 4);
        }
        // B-frags from global pre-split W (L2-hot)
        bf16x8 bfr[2][4];
#pragma unroll
        for (int ks = 0; ks < 2; ++ks)
#pragma unroll
            for (int ni = 0; ni < 4; ++ni)
                bfr[ks][ni] = *(const bf16x8*)(
                    WS + (size_t)(wn + ni * 16 + lr) * 512 + k * 64 + ks * 32 + lq * 8);
        // MFMA over AT[k&1]
#pragma unroll
        for (int ks = 0; ks < 2; ++ks) {
            bf16x8 af[4];
#pragma unroll
            for (int mi = 0; mi < 4; ++mi)
                af[mi] = *(const bf16x8*)&AT[k & 1][(wm + mi * 16 + lr) * AROW + ks * 32 + lq * 8];
#pragma unroll
            for (int mi = 0; mi < 4; ++mi)
#pragma unroll
                for (int ni = 0; ni < 4; ++ni)
                    acc[mi][ni] = __builtin_amdgcn_mfma_f32_16x16x32_bf16(
                        af[mi], bfr[ks][ni], acc[mi][ni], 0, 0, 0);
        }
    }

    // epilogue: C/D layout col=lane&15, row=(lane>>4)*4+reg
#pragma unroll
    for (int mi = 0; mi < 4; ++mi)
#pragma unroll
        for (int ni = 0; ni < 4; ++ni)
#pragma unroll
            for (int reg = 0; reg < 4; ++reg) {
                const int row = p_base + wm + mi * 16 + lq * 4 + reg;
                Y[(size_t)row * CC + wn + ni * 16 + lr] = acc[mi][ni][reg];
            }
}

// ---------------------------------------------------------------------------
// Kernel 2: local 5x5 attention, T=2 row-paired, 16-ch chunks, DMA dbuf.
// Block = 64 threads (1 wave) = 16x8 px tile, thread owns px (r,c),(r+1,c).
// Halo 12x20 = 240 px; chunk = 16 ch = 15 KB; dbuf 30 KB. 12 phases
// (8 k + 4 v); chunk p+1 DMA'd right after the barrier so the vmcnt(0)
// drain lands after ~2.5K cycles of compute. Shared halo rows r..r+5 are
// read once and FMA'd into both pixels' logits/accumulators (1.67x DS cut).
// OOB: staged addresses clamped (never used); invalid logits forced to 0
// pre-softmax and weights to 0 post-softmax == reference zero-padding.
// ---------------------------------------------------------------------------
#define T_W 16
#define T_H 8
#define HALO_W 20
#define HPX 240          // 12*20
#define CH_SLOTS (HPX * 4)   // 960 float4 slots per 16-ch chunk

__global__ __launch_bounds__(64, 2)
void attn_kernel(const float* __restrict__ qm, const float* __restrict__ kr,
                 const float* __restrict__ vv, float* __restrict__ out) {
    __shared__ float4 KS[2][CH_SLOTS];   // 30 KB

    const int t  = threadIdx.x;              // 0..63
    const int bi = blockIdx.x >> 7;          // batch
    const int tile = blockIdx.x & 127;
    const int ty = tile >> 3;                // 16 tile-rows (8 px tall)
    const int tx = tile & 7;                 // 8 tile-cols (16 px wide)
    const int h0 = ty * T_H, w0 = tx * T_W;
    const int c = t & 15;
    const int r = (t >> 4) * 2;              // 0,2,4,6
    const int gbase = bi * HH * WW;
    const int pix0 = gbase + (h0 + r) * WW + (w0 + c);
    const int pix1 = pix0 + WW;

    // validity masks for both pixels
    unsigned vm0 = 0, vm1 = 0;
#pragma unroll
    for (int dy = 0; dy < 5; ++dy)
#pragma unroll
        for (int dx = 0; dx < 5; ++dx) {
            const int ww = w0 + c + dx - 2;
            const bool cok = (unsigned)ww < (unsigned)WW;
            const int h_a = h0 + r + dy - 2;
            const int h_b = h_a + 1;
            if (cok && (unsigned)h_a < (unsigned)HH) vm0 |= 1u << (dy * 5 + dx);
            if (cok && (unsigned)h_b < (unsigned)HH) vm1 |= 1u << (dy * 5 + dx);
        }

    auto stage = [&](int phase, int buf) {
        const float* src = (phase < 8) ? kr : vv;
        const int ld = (phase < 8) ? CC : BIN;
        const int ch = (phase < 8) ? phase * 16 : (phase - 8) * 16;
#pragma unroll
        for (int i = 0; i < 15; ++i) {
            const int s  = i * 64 + t;          // 0..959
            const int g  = s / HPX;             // 0..3
            const int px = s - g * HPX;
            const int py = px / HALO_W;
            const int pxx = px - py * HALO_W;
            int hh = h0 + py - 2;  hh = hh < 0 ? 0 : (hh > HH - 1 ? HH - 1 : hh);
            int ww = w0 + pxx - 2; ww = ww < 0 ? 0 : (ww > WW - 1 ? WW - 1 : ww);
            const float* gp = src + (size_t)(gbase + hh * WW + ww) * ld + ch + g * 4;
            __builtin_amdgcn_global_load_lds(
                (const __attribute__((address_space(1))) void*)gp,
                (__attribute__((address_space(3))) void*)&KS[buf][i * 64],
                16, 0, 0);
        }
    };

    float lg0[25], lg1[25];
#pragma unroll
    for (int i = 0; i < 25; ++i) { lg0[i] = 0.0f; lg1[i] = 0.0f; }

    stage(0, 0);

    // ---- 8 logit phases (16 ch each) ----
    for (int p = 0; p < 8; ++p) {
        __syncthreads();                 // drains DMA(p); DMA(p+1) not yet issued
        stage(p + 1, (p + 1) & 1);       // overlaps with compute below
        float4 q0[4], q1[4];
        {
            const float4* qp0 = (const float4*)(qm + (size_t)pix0 * CC + p * 16);
            const float4* qp1 = (const float4*)(qm + (size_t)pix1 * CC + p * 16);
#pragma unroll
            for (int g = 0; g < 4; ++g) { q0[g] = qp0[g]; q1[g] = qp1[g]; }
        }
        const float4* B = KS[p & 1];
#pragma unroll
        for (int dy2 = 0; dy2 < 6; ++dy2) {
            const int hbase = (r + dy2) * HALO_W + c;
#pragma unroll
            for (int dx = 0; dx < 5; ++dx) {
                const int hp = hbase + dx;
#pragma unroll
                for (int g = 0; g < 4; ++g) {
                    float4 kv = B[g * HPX + hp];
                    if (dy2 < 5)
                        lg0[dy2 * 5 + dx] += q0[g].x * kv.x + q0[g].y * kv.y +
                                             q0[g].z * kv.z + q0[g].w * kv.w;
                    if (dy2 >= 1)
                        lg1[(dy2 - 1) * 5 + dx] += q1[g].x * kv.x + q1[g].y * kv.y +
                                                   q1[g].z * kv.z + q1[g].w * kv.w;
                }
            }
        }
    }

    // ---- softmax for both pixels (overlaps with DMA of v-chunk 0) ----
    {
#pragma unroll
        for (int kk = 0; kk < 25; ++kk) {
            if (!((vm0 >> kk) & 1)) lg0[kk] = 0.0f;
            if (!((vm1 >> kk) & 1)) lg1[kk] = 0.0f;
        }
        float m0 = lg0[0], m1 = lg1[0];
#pragma unroll
        for (int kk = 1; kk < 25; ++kk) { m0 = fmaxf(m0, lg0[kk]); m1 = fmaxf(m1, lg1[kk]); }
        float s0 = 0.0f, s1 = 0.0f;
#pragma unroll
        for (int kk = 0; kk < 25; ++kk) {
            lg0[kk] = __expf(lg0[kk] - m0); s0 += lg0[kk];
            lg1[kk] = __expf(lg1[kk] - m1); s1 += lg1[kk];
        }
        const float i0 = 1.0f / s0, i1 = 1.0f / s1;
#pragma unroll
        for (int kk = 0; kk < 25; ++kk) {
            lg0[kk] = ((vm0 >> kk) & 1) ? lg0[kk] * i0 : 0.0f;
            lg1[kk] = ((vm1 >> kk) & 1) ? lg1[kk] * i1 : 0.0f;
        }
    }

    // ---- 4 value phases (16 bins each) ----
    for (int p = 8; p < 12; ++p) {
        __syncthreads();
        if (p < 11) stage(p + 1, (p + 1) & 1);
        const float4* B = KS[p & 1];
        float4 va0[4], va1[4];
#pragma unroll
        for (int g = 0; g < 4; ++g) {
            va0[g] = make_float4(0.f, 0.f, 0.f, 0.f);
            va1[g] = make_float4(0.f, 0.f, 0.f, 0.f);
        }
#pragma unroll
        for (int dy2 = 0; dy2 < 6; ++dy2) {
            const int hbase = (r + dy2) * HALO_W + c;
#pragma unroll
            for (int dx = 0; dx < 5; ++dx) {
                const int hp = hbase + dx;
                const float w_0 = (dy2 < 5) ? lg0[dy2 * 5 + dx] : 0.0f;
                const float w_1 = (dy2 >= 1) ? lg1[(dy2 - 1) * 5 + dx] : 0.0f;
#pragma unroll
                for (int g = 0; g < 4; ++g) {
                    float4 kv = B[g * HPX + hp];
                    if (dy2 < 5) {
                        va0[g].x += w_0 * kv.x; va0[g].y += w_0 * kv.y;
                        va0[g].z += w_0 * kv.z; va0[g].w += w_0 * kv.w;
                    }
                    if (dy2 >= 1) {
                        va1[g].x += w_1 * kv.x; va1[g].y += w_1 * kv.y;
                        va1[g].z += w_1 * kv.z; va1[g].w += w_1 * kv.w;
                    }
                }
            }
        }
        const int ch = (p - 8) * 16;
        float4* op0 = (float4*)(out + (size_t)pix0 * BIN + ch);
        float4* op1 = (float4*)(out + (size_t)pix1 * BIN + ch);
#pragma unroll
        for (int g = 0; g < 4; ++g) { op0[g] = va0[g]; op1[g] = va1[g]; }
    }
}

extern "C" void kernel_launch(void* const* d_in, const int* in_sizes, int n_in,
                              void* d_out, int out_size, void* d_ws, size_t ws_size,
                              hipStream_t stream) {
    const float* main_in   = (const float*)d_in[0];
    const float* ref_in    = (const float*)d_in[1];
    const float* ref_value = (const float*)d_in[2];
    const float* W_main    = (const float*)d_in[3];
    const float* W_ref     = (const float*)d_in[4];
    float* out = (float*)d_out;

    float* conv_main = (float*)d_ws;                       // 32 MB
    float* conv_ref  = conv_main + (size_t)NPIX * CC;      // 32 MB
    // pre-split W parked in d_out (256 KB of 16.8 MB); attn overwrites d_out
    // entirely afterwards (stream-ordered), so this is safe scratch.
    unsigned short* WS = (unsigned short*)d_out;

    presplit_w_kernel<<<128, 256, 0, stream>>>(W_main, W_ref, WS);

    dim3 gconv(NPIX / 128, 2);   // 1024 blocks
    conv_mfma_kernel<<<gconv, 256, 0, stream>>>(main_in, ref_in, WS,
                                                conv_main, conv_ref);

    // 512 blocks = 2/CU: one 16x8 tile each
    attn_kernel<<<512, 64, 0, stream>>>(conv_main, conv_ref, ref_value, out);
}